// Round 1
// baseline (11993.360 us; speedup 1.0000x reference)
//
#include <hip/hip_runtime.h>
#include <cstdint>

// Problem constants (from reference): B=16, H=W=64, C=512, K=3
constexpr int Bn = 16, Hh = 64, Wd = 64, Cc = 512;
constexpr int HW = Hh * Wd;                 // 4096
constexpr int M_TOT = Bn * HW;              // 65536
constexpr size_t QKV_ELEMS = (size_t)M_TOT * Cc;  // 33,554,432 floats
#define BN_EPS 1e-3f

// ---------------------------------------------------------------------------
// Conv3x3 (SAME) + BN + ReLU as implicit GEMM.
// M = B*H*W = 65536 spatial rows, N = 512 out-channels, K = 9 taps * 512.
// Tile 128x128, BK=8, 256 threads, 8x8 per-thread micro-tile.
// grid = (4, 512)
// ---------------------------------------------------------------------------
__global__ __launch_bounds__(256, 2)
void conv_bn_relu_k(const float* __restrict__ x, const float* __restrict__ Wt,
                    const float* __restrict__ bias, const float* __restrict__ gamma,
                    const float* __restrict__ beta, const float* __restrict__ mean,
                    const float* __restrict__ var, float* __restrict__ out)
{
    __shared__ __align__(16) float As[8][128];   // [k][m] (transposed store)
    __shared__ __align__(16) float Bs[8][132];   // [k][n] (+pad)

    const int t    = threadIdx.x;
    const int brow = blockIdx.y * 128;   // spatial tile
    const int bcol = blockIdx.x * 128;   // out-channel tile

    // A-load mapping: 128 rows x 8 ch, 2 threads/row (float4 each)
    const int ar  = t >> 1;
    const int ah  = (t & 1) << 2;
    const int m   = brow + ar;
    const int bb  = m >> 12;
    const int hh0 = (m >> 6) & 63;
    const int ww0 = m & 63;

    // B-load mapping: 8 rows x 128 cols, 32 threads/row (float4 each)
    const int br2 = t >> 5;
    const int bc2 = (t & 31) << 2;

    // compute mapping: 16x16 threads, 8x8 outputs each
    const int tx = t & 15, ty = t >> 4;

    float acc[8][8] = {};

    for (int tap = 0; tap < 9; ++tap) {
        const int dy = tap / 3 - 1, dx = tap % 3 - 1;
        const int hh = hh0 + dy, ww = ww0 + dx;
        const bool valid = (hh >= 0) && (hh < Hh) && (ww >= 0) && (ww < Wd);
        const float* aptr = x + ((size_t)(bb * HW + hh * Wd + ww) * Cc + ah);
        const float* bptr = Wt + ((size_t)(tap * Cc + br2) * Cc + bcol + bc2);

        float4 av = make_float4(0.f, 0.f, 0.f, 0.f);
        if (valid) av = *(const float4*)(aptr);
        float4 bv = *(const float4*)(bptr);

        for (int ck = 0; ck < Cc; ck += 8) {
            __syncthreads();
            As[ah + 0][ar] = av.x; As[ah + 1][ar] = av.y;
            As[ah + 2][ar] = av.z; As[ah + 3][ar] = av.w;
            *(float4*)&Bs[br2][bc2] = bv;
            __syncthreads();

            float4 av_n = make_float4(0.f, 0.f, 0.f, 0.f);
            float4 bv_n = av_n;
            if (ck + 8 < Cc) {
                if (valid) av_n = *(const float4*)(aptr + ck + 8);
                bv_n = *(const float4*)(bptr + (size_t)(ck + 8) * Cc);
            }

            #pragma unroll
            for (int kk = 0; kk < 8; ++kk) {
                const float4 a0 = *(const float4*)&As[kk][ty * 8];
                const float4 a1 = *(const float4*)&As[kk][ty * 8 + 4];
                const float4 b0 = *(const float4*)&Bs[kk][tx * 8];
                const float4 b1 = *(const float4*)&Bs[kk][tx * 8 + 4];
                const float a[8] = {a0.x, a0.y, a0.z, a0.w, a1.x, a1.y, a1.z, a1.w};
                const float bb2[8] = {b0.x, b0.y, b0.z, b0.w, b1.x, b1.y, b1.z, b1.w};
                #pragma unroll
                for (int i = 0; i < 8; ++i)
                    #pragma unroll
                    for (int j = 0; j < 8; ++j)
                        acc[i][j] = fmaf(a[i], bb2[j], acc[i][j]);
            }
            av = av_n; bv = bv_n;
        }
    }

    float s[8], tt[8];
    #pragma unroll
    for (int j = 0; j < 8; ++j) {
        const int co = bcol + tx * 8 + j;
        const float sc = gamma[co] * rsqrtf(var[co] + BN_EPS);
        s[j]  = sc;
        tt[j] = (bias[co] - mean[co]) * sc + beta[co];
    }
    #pragma unroll
    for (int i = 0; i < 8; ++i) {
        const int mo = brow + ty * 8 + i;
        float v0[8];
        #pragma unroll
        for (int j = 0; j < 8; ++j) v0[j] = fmaxf(fmaf(acc[i][j], s[j], tt[j]), 0.f);
        *(float4*)&out[(size_t)mo * Cc + bcol + tx * 8]     = make_float4(v0[0], v0[1], v0[2], v0[3]);
        *(float4*)&out[(size_t)mo * Cc + bcol + tx * 8 + 4] = make_float4(v0[4], v0[5], v0[6], v0[7]);
    }
}

// ---------------------------------------------------------------------------
// energy[b,c,d] = sum_n q[b,n,c] * k[b,n,d]  (TN-GEMM, both operands k-major)
// M=N=512, K=4096. Tile 128x128, BK=8. grid = (4, 4, 16)
// ---------------------------------------------------------------------------
__global__ __launch_bounds__(256, 2)
void energy_k(const float* __restrict__ q, const float* __restrict__ k,
              float* __restrict__ e)
{
    __shared__ __align__(16) float As[8][132];
    __shared__ __align__(16) float Bs[8][132];

    const int t    = threadIdx.x;
    const int bcol = blockIdx.x * 128;   // d
    const int brow = blockIdx.y * 128;   // c
    const int b    = blockIdx.z;
    const int r2   = t >> 5;
    const int c2   = (t & 31) << 2;
    const int tx   = t & 15, ty = t >> 4;

    const float* qb = q + (size_t)b * HW * Cc;
    const float* kb = k + (size_t)b * HW * Cc;

    float acc[8][8] = {};
    float4 av = *(const float4*)&qb[(size_t)r2 * Cc + brow + c2];
    float4 bv = *(const float4*)&kb[(size_t)r2 * Cc + bcol + c2];

    for (int n0 = 0; n0 < HW; n0 += 8) {
        __syncthreads();
        *(float4*)&As[r2][c2] = av;
        *(float4*)&Bs[r2][c2] = bv;
        __syncthreads();
        if (n0 + 8 < HW) {
            av = *(const float4*)&qb[(size_t)(n0 + 8 + r2) * Cc + brow + c2];
            bv = *(const float4*)&kb[(size_t)(n0 + 8 + r2) * Cc + bcol + c2];
        }
        #pragma unroll
        for (int kk = 0; kk < 8; ++kk) {
            const float4 a0 = *(const float4*)&As[kk][ty * 8];
            const float4 a1 = *(const float4*)&As[kk][ty * 8 + 4];
            const float4 b0 = *(const float4*)&Bs[kk][tx * 8];
            const float4 b1 = *(const float4*)&Bs[kk][tx * 8 + 4];
            const float a[8] = {a0.x, a0.y, a0.z, a0.w, a1.x, a1.y, a1.z, a1.w};
            const float bb2[8] = {b0.x, b0.y, b0.z, b0.w, b1.x, b1.y, b1.z, b1.w};
            #pragma unroll
            for (int i = 0; i < 8; ++i)
                #pragma unroll
                for (int j = 0; j < 8; ++j)
                    acc[i][j] = fmaf(a[i], bb2[j], acc[i][j]);
        }
    }

    #pragma unroll
    for (int i = 0; i < 8; ++i) {
        const size_t base = ((size_t)b * Cc + brow + ty * 8 + i) * Cc + bcol + tx * 8;
        *(float4*)&e[base]     = make_float4(acc[i][0], acc[i][1], acc[i][2], acc[i][3]);
        *(float4*)&e[base + 4] = make_float4(acc[i][4], acc[i][5], acc[i][6], acc[i][7]);
    }
}

// ---------------------------------------------------------------------------
// in-place row softmax over last axis; rows = B*C = 8192, row length 512
// ---------------------------------------------------------------------------
__global__ __launch_bounds__(256)
void softmax_k(float* __restrict__ e)
{
    __shared__ float red[256];
    const int r = blockIdx.x;
    const int t = threadIdx.x;
    float* row = e + (size_t)r * Cc;

    const float v0 = row[t];
    const float v1 = row[t + 256];

    red[t] = fmaxf(v0, v1);
    __syncthreads();
    for (int s = 128; s > 0; s >>= 1) {
        if (t < s) red[t] = fmaxf(red[t], red[t + s]);
        __syncthreads();
    }
    const float mx = red[0];
    __syncthreads();

    const float e0 = expf(v0 - mx);
    const float e1 = expf(v1 - mx);
    red[t] = e0 + e1;
    __syncthreads();
    for (int s = 128; s > 0; s >>= 1) {
        if (t < s) red[t] += red[t + s];
        __syncthreads();
    }
    const float inv = 1.0f / red[0];

    row[t]       = e0 * inv;
    row[t + 256] = e1 * inv;
}

// ---------------------------------------------------------------------------
// pv: out[b, c*HW + n] = aw * sum_d attn[b,c,d] * v[b,n,d] + x[b, c*HW + n]
// (raw reshape => residual add at the same flat index)
// M=512 (c), N=4096 (n), K=512 (d). Tile 128x128, BK=8. grid = (32, 4, 16)
// ---------------------------------------------------------------------------
__global__ __launch_bounds__(256, 2)
void pv_k(const float* __restrict__ attn, const float* __restrict__ v,
          const float* __restrict__ x, const float* __restrict__ aw,
          float* __restrict__ out)
{
    __shared__ __align__(16) float As[8][128];   // [d][c]
    __shared__ __align__(16) float Bs[8][128];   // [d][n]

    const int t    = threadIdx.x;
    const int bn   = blockIdx.x * 128;
    const int brow = blockIdx.y * 128;
    const int b    = blockIdx.z;
    const int ar   = t >> 1;
    const int ah   = (t & 1) << 2;
    const int tx   = t & 15, ty = t >> 4;

    const float* ab = attn + (size_t)b * Cc * Cc;
    const float* vb = v + (size_t)b * HW * Cc;

    float acc[8][8] = {};
    float4 av = *(const float4*)&ab[(size_t)(brow + ar) * Cc + ah];
    float4 bv = *(const float4*)&vb[(size_t)(bn + ar) * Cc + ah];

    for (int d0 = 0; d0 < Cc; d0 += 8) {
        __syncthreads();
        As[ah + 0][ar] = av.x; As[ah + 1][ar] = av.y;
        As[ah + 2][ar] = av.z; As[ah + 3][ar] = av.w;
        Bs[ah + 0][ar] = bv.x; Bs[ah + 1][ar] = bv.y;
        Bs[ah + 2][ar] = bv.z; Bs[ah + 3][ar] = bv.w;
        __syncthreads();
        if (d0 + 8 < Cc) {
            av = *(const float4*)&ab[(size_t)(brow + ar) * Cc + d0 + 8 + ah];
            bv = *(const float4*)&vb[(size_t)(bn + ar) * Cc + d0 + 8 + ah];
        }
        #pragma unroll
        for (int kk = 0; kk < 8; ++kk) {
            const float4 a0 = *(const float4*)&As[kk][ty * 8];
            const float4 a1 = *(const float4*)&As[kk][ty * 8 + 4];
            const float4 b0 = *(const float4*)&Bs[kk][tx * 8];
            const float4 b1 = *(const float4*)&Bs[kk][tx * 8 + 4];
            const float a[8] = {a0.x, a0.y, a0.z, a0.w, a1.x, a1.y, a1.z, a1.w};
            const float bb2[8] = {b0.x, b0.y, b0.z, b0.w, b1.x, b1.y, b1.z, b1.w};
            #pragma unroll
            for (int i = 0; i < 8; ++i)
                #pragma unroll
                for (int j = 0; j < 8; ++j)
                    acc[i][j] = fmaf(a[i], bb2[j], acc[i][j]);
        }
    }

    const float a_w = aw[0];
    #pragma unroll
    for (int i = 0; i < 8; ++i) {
        const int c = brow + ty * 8 + i;
        const size_t base = (size_t)b * ((size_t)Cc * HW) + (size_t)c * HW + bn + tx * 8;
        const float4 x0 = *(const float4*)&x[base];
        const float4 x1 = *(const float4*)&x[base + 4];
        *(float4*)&out[base] = make_float4(fmaf(a_w, acc[i][0], x0.x),
                                           fmaf(a_w, acc[i][1], x0.y),
                                           fmaf(a_w, acc[i][2], x0.z),
                                           fmaf(a_w, acc[i][3], x0.w));
        *(float4*)&out[base + 4] = make_float4(fmaf(a_w, acc[i][4], x1.x),
                                               fmaf(a_w, acc[i][5], x1.y),
                                               fmaf(a_w, acc[i][6], x1.z),
                                               fmaf(a_w, acc[i][7], x1.w));
    }
}

// ---------------------------------------------------------------------------
extern "C" void kernel_launch(void* const* d_in, const int* in_sizes, int n_in,
                              void* d_out, int out_size, void* d_ws, size_t ws_size,
                              hipStream_t stream)
{
    const float* x   = (const float*)d_in[0];
    const float* Wq  = (const float*)d_in[1];
    const float* bq  = (const float*)d_in[2];
    const float* Wk  = (const float*)d_in[3];
    const float* bk  = (const float*)d_in[4];
    const float* Wv  = (const float*)d_in[5];
    const float* bvv = (const float*)d_in[6];
    const float* qg  = (const float*)d_in[7];
    const float* qbt = (const float*)d_in[8];
    const float* qm  = (const float*)d_in[9];
    const float* qv  = (const float*)d_in[10];
    const float* kg  = (const float*)d_in[11];
    const float* kbt = (const float*)d_in[12];
    const float* km  = (const float*)d_in[13];
    const float* kv  = (const float*)d_in[14];
    const float* vg  = (const float*)d_in[15];
    const float* vbt = (const float*)d_in[16];
    const float* vm  = (const float*)d_in[17];
    const float* vvr = (const float*)d_in[18];
    const float* aw  = (const float*)d_in[19];
    float* out = (float*)d_out;

    // workspace: q | k | v | energy  (400 MiB total; fully rewritten per call)
    float* q  = (float*)d_ws;
    float* kk = q + QKV_ELEMS;
    float* vv = kk + QKV_ELEMS;
    float* e  = vv + QKV_ELEMS;

    const dim3 blk(256);
    const dim3 cgrid(4, 512);

    hipLaunchKernelGGL(conv_bn_relu_k, cgrid, blk, 0, stream, x, Wq, bq, qg, qbt, qm, qv, q);
    hipLaunchKernelGGL(conv_bn_relu_k, cgrid, blk, 0, stream, x, Wk, bk, kg, kbt, km, kv, kk);
    hipLaunchKernelGGL(conv_bn_relu_k, cgrid, blk, 0, stream, x, Wv, bvv, vg, vbt, vm, vvr, vv);
    hipLaunchKernelGGL(energy_k, dim3(4, 4, 16), blk, 0, stream, q, kk, e);
    hipLaunchKernelGGL(softmax_k, dim3(8192), blk, 0, stream, e);
    hipLaunchKernelGGL(pv_k, dim3(32, 4, 16), blk, 0, stream, e, vv, x, aw, out);
}

// Round 2
// 3073.569 us; speedup vs baseline: 3.9021x; 3.9021x over previous
//
#include <hip/hip_runtime.h>
#include <cstdint>

constexpr int Hh = 64, Wd = 64, Cc = 512;
constexpr int HW = 4096;
#define BN_EPS 1e-3f

typedef __attribute__((ext_vector_type(8))) short short8;
typedef __attribute__((ext_vector_type(4))) float f32x4;

__device__ __forceinline__ void gld16(const void* g, void* l) {
    __builtin_amdgcn_global_load_lds((const __attribute__((address_space(1))) void*)g,
                                     (__attribute__((address_space(3))) void*)l, 16, 0, 0);
}
__device__ __forceinline__ unsigned short bf_rne(float f) {
    uint32_t u = __float_as_uint(f);
    return (unsigned short)((u + 0x7fffu + ((u >> 16) & 1u)) >> 16);
}
// f = hi(trunc) + rest ; lo = RNE(rest)  (unbiased residual)
__device__ __forceinline__ void split2(float f, unsigned short& hi, unsigned short& lo) {
    uint32_t u = __float_as_uint(f);
    hi = (unsigned short)(u >> 16);
    float hf = __uint_as_float(u & 0xffff0000u);
    lo = bf_rne(f - hf);
}

struct StageLds { short Ah[128][32]; short Al[128][32]; short Bh[128][32]; short Bl[128][32]; };
union  ConvLds  { StageLds s; short T[128][136]; };

// ---------------------------------------------------------------------------
// W [tap][cin][cout] fp32 -> Wt_hi/lo [cout][tap*512+cin] bf16. grid (16,16,9)
// ---------------------------------------------------------------------------
__global__ __launch_bounds__(256)
void wsplit_k(const float* __restrict__ W, unsigned short* __restrict__ wh,
              unsigned short* __restrict__ wl)
{
    __shared__ float T[32][33];
    const int tap = blockIdx.z, ci0 = blockIdx.x * 32, co0 = blockIdx.y * 32;
    const int t = threadIdx.x;
    const int ci = t >> 5, co = t & 31;
    #pragma unroll
    for (int rep = 0; rep < 4; ++rep)
        T[ci + rep * 8][co] = W[(size_t)((tap * Cc) + ci0 + ci + rep * 8) * Cc + co0 + co];
    __syncthreads();
    const int co2 = t >> 5, ci2 = t & 31;
    #pragma unroll
    for (int rep = 0; rep < 4; ++rep) {
        float v = T[ci2][co2 + rep * 8];
        unsigned short h, l; split2(v, h, l);
        size_t addr = (size_t)(co0 + co2 + rep * 8) * 4608 + (size_t)tap * Cc + ci0 + ci2;
        wh[addr] = h; wl[addr] = l;
    }
}

// ---------------------------------------------------------------------------
// Conv3x3 SAME + BN + ReLU, implicit GEMM, split-bf16 (3 MFMA products).
// out[cout][m] = sum_k Wt[cout][k] * xim[m][k].  grid (4, 32, 16)
// MODE 0: store transposed hi/lo (q_t,k_t [b][c][n]); MODE 1: store v [b][n][c] bf16.
// ---------------------------------------------------------------------------
template<int MODE>
__global__ __launch_bounds__(256, 2)
void conv_k(const float* __restrict__ x,
            const unsigned short* __restrict__ wh, const unsigned short* __restrict__ wl,
            const float* __restrict__ bias, const float* __restrict__ gamma,
            const float* __restrict__ beta, const float* __restrict__ mean,
            const float* __restrict__ var,
            unsigned short* __restrict__ oh, unsigned short* __restrict__ ol)
{
    __shared__ ConvLds lds;
    const int t = threadIdx.x;
    const int bcout = blockIdx.x * 128;
    const int m0    = blockIdx.y * 128;
    const int b     = blockIdx.z;
    const int lane = t & 63, wave = t >> 6;
    const int wr = wave >> 1, wc = wave & 1;

    const int row0 = t >> 2, k00 = (t & 3) * 8;   // chunk t ; chunk t+256 -> row0+64
    const int m_r0 = m0 + row0, m_r1 = m0 + row0 + 64;
    const int h0 = m_r0 >> 6, w0 = m_r0 & 63;
    const int h1 = m_r1 >> 6, w1 = m_r1 & 63;

    f32x4 acc[4][4] = {};
    float xv[16];

    auto loadx = [&](int ks) {
        const int tap = ks >> 4;
        const int ck  = (ks & 15) << 5;
        const int dy = tap / 3 - 1, dx = tap % 3 - 1;
        {
            const int hh = h0 + dy, ww = w0 + dx;
            if ((unsigned)hh < 64u && (unsigned)ww < 64u) {
                const float* p = x + ((size_t)((b * Hh + hh) * Wd + ww)) * Cc + ck + k00;
                float4 u0 = *(const float4*)p;
                float4 u1 = *(const float4*)(p + 4);
                xv[0]=u0.x; xv[1]=u0.y; xv[2]=u0.z; xv[3]=u0.w;
                xv[4]=u1.x; xv[5]=u1.y; xv[6]=u1.z; xv[7]=u1.w;
            } else {
                #pragma unroll
                for (int q2 = 0; q2 < 8; ++q2) xv[q2] = 0.f;
            }
        }
        {
            const int hh = h1 + dy, ww = w1 + dx;
            if ((unsigned)hh < 64u && (unsigned)ww < 64u) {
                const float* p = x + ((size_t)((b * Hh + hh) * Wd + ww)) * Cc + ck + k00;
                float4 u0 = *(const float4*)p;
                float4 u1 = *(const float4*)(p + 4);
                xv[8]=u0.x; xv[9]=u0.y; xv[10]=u0.z; xv[11]=u0.w;
                xv[12]=u1.x; xv[13]=u1.y; xv[14]=u1.z; xv[15]=u1.w;
            } else {
                #pragma unroll
                for (int q2 = 0; q2 < 8; ++q2) xv[8 + q2] = 0.f;
            }
        }
    };

    loadx(0);

    for (int ks = 0; ks < 144; ++ks) {
        const int tap = ks >> 4;
        const size_t kb = (size_t)tap * Cc + ((ks & 15) << 5) + k00;
        // A: Wt hi/lo via global_load_lds (dest linear, lane*16B)
        gld16(wh + (size_t)(bcout + row0)      * 4608 + kb, (short*)&lds.s.Ah[0][0] + t * 8);
        gld16(wh + (size_t)(bcout + row0 + 64) * 4608 + kb, (short*)&lds.s.Ah[0][0] + t * 8 + 2048);
        gld16(wl + (size_t)(bcout + row0)      * 4608 + kb, (short*)&lds.s.Al[0][0] + t * 8);
        gld16(wl + (size_t)(bcout + row0 + 64) * 4608 + kb, (short*)&lds.s.Al[0][0] + t * 8 + 2048);
        // B: split xv -> hi/lo tiles
        {
            short8 hv, lv;
            #pragma unroll
            for (int q2 = 0; q2 < 8; ++q2) { unsigned short h, l; split2(xv[q2], h, l); hv[q2] = (short)h; lv[q2] = (short)l; }
            *(short8*)&lds.s.Bh[row0][k00] = hv;
            *(short8*)&lds.s.Bl[row0][k00] = lv;
            #pragma unroll
            for (int q2 = 0; q2 < 8; ++q2) { unsigned short h, l; split2(xv[8 + q2], h, l); hv[q2] = (short)h; lv[q2] = (short)l; }
            *(short8*)&lds.s.Bh[row0 + 64][k00] = hv;
            *(short8*)&lds.s.Bl[row0 + 64][k00] = lv;
        }
        __builtin_amdgcn_sched_barrier(0);
        asm volatile("s_waitcnt vmcnt(0) lgkmcnt(0)" ::: "memory");
        __builtin_amdgcn_sched_barrier(0);
        if (ks + 1 < 144) loadx(ks + 1);   // overlaps compute; consumed next iter
        __builtin_amdgcn_s_barrier();

        short8 ah[4], al[4];
        const int kq = (lane >> 4) * 8;
        #pragma unroll
        for (int i = 0; i < 4; ++i) {
            const int r = wr * 64 + i * 16 + (lane & 15);
            ah[i] = *(const short8*)&lds.s.Ah[r][kq];
            al[i] = *(const short8*)&lds.s.Al[r][kq];
        }
        #pragma unroll
        for (int j = 0; j < 4; ++j) {
            const int r = wc * 64 + j * 16 + (lane & 15);
            short8 bh = *(const short8*)&lds.s.Bh[r][kq];
            short8 bl = *(const short8*)&lds.s.Bl[r][kq];
            #pragma unroll
            for (int i = 0; i < 4; ++i) {
                acc[i][j] = __builtin_amdgcn_mfma_f32_16x16x32_bf16(ah[i], bh, acc[i][j], 0, 0, 0);
                acc[i][j] = __builtin_amdgcn_mfma_f32_16x16x32_bf16(ah[i], bl, acc[i][j], 0, 0, 0);
                acc[i][j] = __builtin_amdgcn_mfma_f32_16x16x32_bf16(al[i], bh, acc[i][j], 0, 0, 0);
            }
        }
        __builtin_amdgcn_s_barrier();
    }

    if (MODE == 0) {
        #pragma unroll
        for (int i = 0; i < 4; ++i) {
            #pragma unroll
            for (int r = 0; r < 4; ++r) {
                const int co = bcout + wr * 64 + i * 16 + (lane >> 4) * 4 + r;
                const float sc = gamma[co] * rsqrtf(var[co] + BN_EPS);
                const float tb = (bias[co] - mean[co]) * sc + beta[co];
                const size_t rowbase = ((size_t)(b * Cc + co)) * HW;
                #pragma unroll
                for (int j = 0; j < 4; ++j) {
                    const int n = m0 + wc * 64 + j * 16 + (lane & 15);
                    const float y = fmaxf(fmaf(acc[i][j][r], sc, tb), 0.f);
                    unsigned short h, l; split2(y, h, l);
                    oh[rowbase + n] = h; ol[rowbase + n] = l;
                }
            }
        }
    } else {
        // v: bf16 single, transpose through LDS to [n][c]
        #pragma unroll
        for (int i = 0; i < 4; ++i) {
            #pragma unroll
            for (int r = 0; r < 4; ++r) {
                const int cl = wr * 64 + i * 16 + (lane >> 4) * 4 + r;
                const int co = bcout + cl;
                const float sc = gamma[co] * rsqrtf(var[co] + BN_EPS);
                const float tb = (bias[co] - mean[co]) * sc + beta[co];
                #pragma unroll
                for (int j = 0; j < 4; ++j) {
                    const int nl = wc * 64 + j * 16 + (lane & 15);
                    const float y = fmaxf(fmaf(acc[i][j][r], sc, tb), 0.f);
                    lds.T[nl][cl] = (short)bf_rne(y);
                }
            }
        }
        __syncthreads();
        #pragma unroll
        for (int rep = 0; rep < 4; ++rep) {
            const int nl = (t >> 3) + rep * 32;
            const int c0l = (t & 7) * 16;
            short8 v0 = *(const short8*)&lds.T[nl][c0l];
            short8 v1 = *(const short8*)&lds.T[nl][c0l + 8];
            const size_t base = ((size_t)(b * HW + m0 + nl)) * Cc + bcout + c0l;
            *(short8*)&oh[base] = v0;
            *(short8*)&oh[base + 8] = v1;
        }
    }
    (void)ol;
}

// ---------------------------------------------------------------------------
// energy[b][c][d] = sum_n q_t[c][n] k_t[d][n], split-bf16, split-K=2.
// grid (4, 4, 32): z = b*2 + half -> e_a / e_b partials.
// ---------------------------------------------------------------------------
__global__ __launch_bounds__(256, 2)
void energy_k(const unsigned short* __restrict__ qh, const unsigned short* __restrict__ ql,
              const unsigned short* __restrict__ kh, const unsigned short* __restrict__ kl,
              float* __restrict__ ea, float* __restrict__ eb)
{
    __shared__ StageLds lds;
    const int t = threadIdx.x;
    const int d0 = blockIdx.x * 128;
    const int c0 = blockIdx.y * 128;
    const int b  = blockIdx.z >> 1;
    const int nb0 = (blockIdx.z & 1) * 2048;
    float* __restrict__ eo = (blockIdx.z & 1) ? eb : ea;
    const int lane = t & 63, wave = t >> 6, wr = wave >> 1, wc = wave & 1;
    const int row0 = t >> 2, k00 = (t & 3) * 8;

    const size_t qb = (size_t)b * Cc * HW;
    f32x4 acc[4][4] = {};

    for (int ks = 0; ks < 64; ++ks) {
        const size_t nb = nb0 + ks * 32 + k00;
        gld16(qh + qb + (size_t)(c0 + row0)      * HW + nb, (short*)&lds.Ah[0][0] + t * 8);
        gld16(qh + qb + (size_t)(c0 + row0 + 64) * HW + nb, (short*)&lds.Ah[0][0] + t * 8 + 2048);
        gld16(ql + qb + (size_t)(c0 + row0)      * HW + nb, (short*)&lds.Al[0][0] + t * 8);
        gld16(ql + qb + (size_t)(c0 + row0 + 64) * HW + nb, (short*)&lds.Al[0][0] + t * 8 + 2048);
        gld16(kh + qb + (size_t)(d0 + row0)      * HW + nb, (short*)&lds.Bh[0][0] + t * 8);
        gld16(kh + qb + (size_t)(d0 + row0 + 64) * HW + nb, (short*)&lds.Bh[0][0] + t * 8 + 2048);
        gld16(kl + qb + (size_t)(d0 + row0)      * HW + nb, (short*)&lds.Bl[0][0] + t * 8);
        gld16(kl + qb + (size_t)(d0 + row0 + 64) * HW + nb, (short*)&lds.Bl[0][0] + t * 8 + 2048);
        __builtin_amdgcn_sched_barrier(0);
        asm volatile("s_waitcnt vmcnt(0)" ::: "memory");
        __builtin_amdgcn_s_barrier();

        short8 ah[4], al[4];
        const int kq = (lane >> 4) * 8;
        #pragma unroll
        for (int i = 0; i < 4; ++i) {
            const int r = wr * 64 + i * 16 + (lane & 15);
            ah[i] = *(const short8*)&lds.Ah[r][kq];
            al[i] = *(const short8*)&lds.Al[r][kq];
        }
        #pragma unroll
        for (int j = 0; j < 4; ++j) {
            const int r = wc * 64 + j * 16 + (lane & 15);
            short8 bh = *(const short8*)&lds.Bh[r][kq];
            short8 bl = *(const short8*)&lds.Bl[r][kq];
            #pragma unroll
            for (int i = 0; i < 4; ++i) {
                acc[i][j] = __builtin_amdgcn_mfma_f32_16x16x32_bf16(ah[i], bh, acc[i][j], 0, 0, 0);
                acc[i][j] = __builtin_amdgcn_mfma_f32_16x16x32_bf16(ah[i], bl, acc[i][j], 0, 0, 0);
                acc[i][j] = __builtin_amdgcn_mfma_f32_16x16x32_bf16(al[i], bh, acc[i][j], 0, 0, 0);
            }
        }
        __builtin_amdgcn_s_barrier();
    }
    #pragma unroll
    for (int i = 0; i < 4; ++i)
        #pragma unroll
        for (int r = 0; r < 4; ++r) {
            const int c = c0 + wr * 64 + i * 16 + (lane >> 4) * 4 + r;
            #pragma unroll
            for (int j = 0; j < 4; ++j) {
                const int d = d0 + wc * 64 + j * 16 + (lane & 15);
                eo[((size_t)(b * Cc) + c) * Cc + d] = acc[i][j][r];
            }
        }
}

// ---------------------------------------------------------------------------
// softmax rows (B*C = 8192), adds split-K partials, writes bf16 attn
// ---------------------------------------------------------------------------
__global__ __launch_bounds__(256)
void softmax_k(const float* __restrict__ ea, const float* __restrict__ eb,
               unsigned short* __restrict__ attn)
{
    __shared__ float red[256];
    const int r = blockIdx.x, t = threadIdx.x;
    const size_t base = (size_t)r * Cc;
    const float v0 = ea[base + t] + eb[base + t];
    const float v1 = ea[base + t + 256] + eb[base + t + 256];

    red[t] = fmaxf(v0, v1);
    __syncthreads();
    for (int s = 128; s > 0; s >>= 1) {
        if (t < s) red[t] = fmaxf(red[t], red[t + s]);
        __syncthreads();
    }
    const float mx = red[0];
    __syncthreads();
    const float e0 = expf(v0 - mx);
    const float e1 = expf(v1 - mx);
    red[t] = e0 + e1;
    __syncthreads();
    for (int s = 128; s > 0; s >>= 1) {
        if (t < s) red[t] += red[t + s];
        __syncthreads();
    }
    const float inv = 1.0f / red[0];
    attn[base + t]       = bf_rne(e0 * inv);
    attn[base + t + 256] = bf_rne(e1 * inv);
}

// ---------------------------------------------------------------------------
// pv: out[b][c*HW+n] = aw * sum_d attn[c][d] v[n][d] + x[same flat]. grid (32,4,16)
// ---------------------------------------------------------------------------
struct PvLds { short Ah[128][32]; short Bh[128][32]; };

__global__ __launch_bounds__(256, 2)
void pv_k(const unsigned short* __restrict__ attn, const unsigned short* __restrict__ v,
          const float* __restrict__ x, const float* __restrict__ aw,
          float* __restrict__ out)
{
    __shared__ PvLds lds;
    const int t = threadIdx.x;
    const int m0 = blockIdx.x * 128;
    const int c0 = blockIdx.y * 128;
    const int b  = blockIdx.z;
    const int lane = t & 63, wave = t >> 6, wr = wave >> 1, wc = wave & 1;
    const int row0 = t >> 2, k00 = (t & 3) * 8;

    f32x4 acc[4][4] = {};
    const size_t ab = (size_t)b * Cc * Cc;
    const size_t vb = (size_t)b * HW * Cc;

    for (int ks = 0; ks < 16; ++ks) {
        const size_t db = ks * 32 + k00;
        gld16(attn + ab + (size_t)(c0 + row0)      * Cc + db, (short*)&lds.Ah[0][0] + t * 8);
        gld16(attn + ab + (size_t)(c0 + row0 + 64) * Cc + db, (short*)&lds.Ah[0][0] + t * 8 + 2048);
        gld16(v + vb + (size_t)(m0 + row0)      * Cc + db, (short*)&lds.Bh[0][0] + t * 8);
        gld16(v + vb + (size_t)(m0 + row0 + 64) * Cc + db, (short*)&lds.Bh[0][0] + t * 8 + 2048);
        __builtin_amdgcn_sched_barrier(0);
        asm volatile("s_waitcnt vmcnt(0)" ::: "memory");
        __builtin_amdgcn_s_barrier();

        short8 ah[4];
        const int kq = (lane >> 4) * 8;
        #pragma unroll
        for (int i = 0; i < 4; ++i)
            ah[i] = *(const short8*)&lds.Ah[wr * 64 + i * 16 + (lane & 15)][kq];
        #pragma unroll
        for (int j = 0; j < 4; ++j) {
            short8 bh = *(const short8*)&lds.Bh[wc * 64 + j * 16 + (lane & 15)][kq];
            #pragma unroll
            for (int i = 0; i < 4; ++i)
                acc[i][j] = __builtin_amdgcn_mfma_f32_16x16x32_bf16(ah[i], bh, acc[i][j], 0, 0, 0);
        }
        __builtin_amdgcn_s_barrier();
    }

    const float a_w = aw[0];
    #pragma unroll
    for (int i = 0; i < 4; ++i)
        #pragma unroll
        for (int r = 0; r < 4; ++r) {
            const int c = c0 + wr * 64 + i * 16 + (lane >> 4) * 4 + r;
            #pragma unroll
            for (int j = 0; j < 4; ++j) {
                const int n = m0 + wc * 64 + j * 16 + (lane & 15);
                const size_t idx = (size_t)b * ((size_t)Cc * HW) + (size_t)c * HW + n;
                out[idx] = fmaf(a_w, acc[i][j][r], x[idx]);
            }
        }
}

// ---------------------------------------------------------------------------
extern "C" void kernel_launch(void* const* d_in, const int* in_sizes, int n_in,
                              void* d_out, int out_size, void* d_ws, size_t ws_size,
                              hipStream_t stream)
{
    (void)in_sizes; (void)n_in; (void)out_size; (void)ws_size;
    const float* x   = (const float*)d_in[0];
    const float* Wq  = (const float*)d_in[1];
    const float* bq  = (const float*)d_in[2];
    const float* Wk  = (const float*)d_in[3];
    const float* bk  = (const float*)d_in[4];
    const float* Wv  = (const float*)d_in[5];
    const float* bvv = (const float*)d_in[6];
    const float* qg  = (const float*)d_in[7];
    const float* qbt = (const float*)d_in[8];
    const float* qm  = (const float*)d_in[9];
    const float* qv  = (const float*)d_in[10];
    const float* kg  = (const float*)d_in[11];
    const float* kbt = (const float*)d_in[12];
    const float* km  = (const float*)d_in[13];
    const float* kv  = (const float*)d_in[14];
    const float* vg  = (const float*)d_in[15];
    const float* vbt = (const float*)d_in[16];
    const float* vm  = (const float*)d_in[17];
    const float* vvr = (const float*)d_in[18];
    const float* aw  = (const float*)d_in[19];
    float* out = (float*)d_out;

    char* w = (char*)d_ws;
    unsigned short* wt_h = (unsigned short*)(w);
    unsigned short* wt_l = (unsigned short*)(w + 4718592);
    unsigned short* q_h  = (unsigned short*)(w + 9437184);
    unsigned short* q_l  = (unsigned short*)(w + 76546048);
    unsigned short* k_h  = (unsigned short*)(w + 143654912);
    unsigned short* k_l  = (unsigned short*)(w + 210763776);
    unsigned short* v_b  = (unsigned short*)(w + 277872640);
    float*          e_a  = (float*)(w + 344981504);
    float*          e_b  = (float*)(w + 361758720);
    unsigned short* attn = (unsigned short*)(w + 378535936);
    // total = 386,924,544 bytes  (< round-1-proven 419,430,400)

    const dim3 blk(256);
    const dim3 wgrid(16, 16, 9);
    const dim3 cgrid(4, 32, 16);

    wsplit_k<<<wgrid, blk, 0, stream>>>(Wq, wt_h, wt_l);
    conv_k<0><<<cgrid, blk, 0, stream>>>(x, wt_h, wt_l, bq, qg, qbt, qm, qv, q_h, q_l);
    wsplit_k<<<wgrid, blk, 0, stream>>>(Wk, wt_h, wt_l);
    conv_k<0><<<cgrid, blk, 0, stream>>>(x, wt_h, wt_l, bk, kg, kbt, km, kv, k_h, k_l);
    wsplit_k<<<wgrid, blk, 0, stream>>>(Wv, wt_h, wt_l);
    conv_k<1><<<cgrid, blk, 0, stream>>>(x, wt_h, wt_l, bvv, vg, vbt, vm, vvr, v_b, nullptr);

    energy_k<<<dim3(4, 4, 32), blk, 0, stream>>>(q_h, q_l, k_h, k_l, e_a, e_b);
    softmax_k<<<dim3(8192), blk, 0, stream>>>(e_a, e_b, attn);
    pv_k<<<dim3(32, 4, 16), blk, 0, stream>>>(attn, v_b, x, aw, out);
}

// Round 3
// 2791.247 us; speedup vs baseline: 4.2968x; 1.1011x over previous
//
#include <hip/hip_runtime.h>
#include <cstdint>

constexpr int Hh = 64, Wd = 64, Cc = 512;
constexpr int HW = 4096;
#define BN_EPS 1e-3f

typedef __attribute__((ext_vector_type(8))) short short8;
typedef __attribute__((ext_vector_type(4))) float f32x4;

__device__ __forceinline__ void gld16(const void* g, void* l) {
    __builtin_amdgcn_global_load_lds((const __attribute__((address_space(1))) void*)g,
                                     (__attribute__((address_space(3))) void*)l, 16, 0, 0);
}
__device__ __forceinline__ unsigned short bf_rne(float f) {
    uint32_t u = __float_as_uint(f);
    return (unsigned short)((u + 0x7fffu + ((u >> 16) & 1u)) >> 16);
}
// f = hi(trunc) + rest ; lo = RNE(rest)  (unbiased residual)
__device__ __forceinline__ void split2(float f, unsigned short& hi, unsigned short& lo) {
    uint32_t u = __float_as_uint(f);
    hi = (unsigned short)(u >> 16);
    float hf = __uint_as_float(u & 0xffff0000u);
    lo = bf_rne(f - hf);
}
// short-index of logical [r][q*8] in a [128 rows][4 slots of 16B] plane,
// slot-swizzled: phys_slot = q ^ ((r>>1)&3)  -> conflict-free ds_read_b128
__device__ __forceinline__ int swz8(int r, int q) {
    return r * 32 + (((q ^ (r >> 1)) & 3) << 3);
}

// ---------------------------------------------------------------------------
// W [tap][cin][cout] fp32 -> Wt_hi/lo [cout][tap*512+cin] bf16. grid (16,16,9)
// ---------------------------------------------------------------------------
__global__ __launch_bounds__(256)
void wsplit_k(const float* __restrict__ W, unsigned short* __restrict__ wh,
              unsigned short* __restrict__ wl)
{
    __shared__ float T[32][33];
    const int tap = blockIdx.z, ci0 = blockIdx.x * 32, co0 = blockIdx.y * 32;
    const int t = threadIdx.x;
    const int ci = t >> 5, co = t & 31;
    #pragma unroll
    for (int rep = 0; rep < 4; ++rep)
        T[ci + rep * 8][co] = W[(size_t)((tap * Cc) + ci0 + ci + rep * 8) * Cc + co0 + co];
    __syncthreads();
    const int co2 = t >> 5, ci2 = t & 31;
    #pragma unroll
    for (int rep = 0; rep < 4; ++rep) {
        float v = T[ci2][co2 + rep * 8];
        unsigned short h, l; split2(v, h, l);
        size_t addr = (size_t)(co0 + co2 + rep * 8) * 4608 + (size_t)tap * Cc + ci0 + ci2;
        wh[addr] = h; wl[addr] = l;
    }
}

// ---------------------------------------------------------------------------
// Conv3x3 SAME + BN + ReLU, implicit GEMM, split-bf16 (3 MFMA products).
// A (weights hi/lo): double-buffered gld16, counted vmcnt.
// B (x): branchless fp32 load -> reg split -> swizzled ds_write (single buf).
// grid 2048 (1D, XCD-swizzled). MODE 0: store [c][n] hi/lo; MODE 1: v [n][c].
// ---------------------------------------------------------------------------
struct ABuf { short Ah[128][32]; short Al[128][32]; };   // 16 KB
struct BBuf { short Bh[128][32]; short Bl[128][32]; };   // 16 KB
union  ConvLds { struct { ABuf a[2]; BBuf b; } s; short T[128][136]; };  // 48 KB

template<int MODE>
__global__ __launch_bounds__(256, 3)
void conv_k(const float* __restrict__ x,
            const unsigned short* __restrict__ wh, const unsigned short* __restrict__ wl,
            const float* __restrict__ bias, const float* __restrict__ gamma,
            const float* __restrict__ beta, const float* __restrict__ mean,
            const float* __restrict__ var,
            unsigned short* __restrict__ oh, unsigned short* __restrict__ ol)
{
    __shared__ ConvLds lds;
    const int t = threadIdx.x;
    const int wg = (blockIdx.x & 7) * 256 + (blockIdx.x >> 3);   // bijective XCD swizzle
    const int bcout = (wg & 3) * 128;
    const int m0    = ((wg >> 2) & 31) * 128;
    const int b     = wg >> 7;
    const int lane = t & 63, wave = t >> 6;
    const int wr = wave >> 1, wc = wave & 1;

    const int row0 = t >> 2;              // 0..63
    const int k00f = (t & 3) * 8;         // logical 8-float chunk in 32-k tile
    const int qlog = (t & 3) ^ ((t >> 3) & 3);   // pre-swizzled source slot for gld16

    const int m_r0 = m0 + row0, m_r1 = m0 + row0 + 64;
    const int h0 = m_r0 >> 6, w0 = m_r0 & 63;
    const int h1 = m_r1 >> 6, w1 = m_r1 & 63;
    const float* xb = x + (size_t)b * HW * Cc;

    f32x4 acc[4][4] = {};
    float xc[16], xn[16];

    // branchless boundary: clamped address (always in-bounds) + multiply mask
    auto loadx = [&](int ks, float* xd) {
        const int tap = ks >> 4;
        const int ck  = (ks & 15) << 5;
        const int dy = tap / 3 - 1, dx = tap % 3 - 1;
        {
            const int hh = h0 + dy, ww = w0 + dx;
            const float msk = ((unsigned)hh < 64u && (unsigned)ww < 64u) ? 1.f : 0.f;
            const int hcl = min(max(hh, 0), 63), wcl = min(max(ww, 0), 63);
            const float* p = xb + ((size_t)(hcl * Wd + wcl)) * Cc + ck + k00f;
            float4 u0 = *(const float4*)p;
            float4 u1 = *(const float4*)(p + 4);
            xd[0] = u0.x * msk; xd[1] = u0.y * msk; xd[2] = u0.z * msk; xd[3] = u0.w * msk;
            xd[4] = u1.x * msk; xd[5] = u1.y * msk; xd[6] = u1.z * msk; xd[7] = u1.w * msk;
        }
        {
            const int hh = h1 + dy, ww = w1 + dx;
            const float msk = ((unsigned)hh < 64u && (unsigned)ww < 64u) ? 1.f : 0.f;
            const int hcl = min(max(hh, 0), 63), wcl = min(max(ww, 0), 63);
            const float* p = xb + ((size_t)(hcl * Wd + wcl)) * Cc + ck + k00f;
            float4 u0 = *(const float4*)p;
            float4 u1 = *(const float4*)(p + 4);
            xd[8]  = u0.x * msk; xd[9]  = u0.y * msk; xd[10] = u0.z * msk; xd[11] = u0.w * msk;
            xd[12] = u1.x * msk; xd[13] = u1.y * msk; xd[14] = u1.z * msk; xd[15] = u1.w * msk;
        }
    };

    auto issueA = [&](int ks, ABuf* ab) {   // 4 gld16, pre-swizzled source col
        const int tap = ks >> 4;
        const size_t kb = (size_t)tap * Cc + ((ks & 15) << 5) + qlog * 8;
        gld16(wh + (size_t)(bcout + row0)      * 4608 + kb, (short*)ab->Ah + t * 8);
        gld16(wh + (size_t)(bcout + row0 + 64) * 4608 + kb, (short*)ab->Ah + t * 8 + 2048);
        gld16(wl + (size_t)(bcout + row0)      * 4608 + kb, (short*)ab->Al + t * 8);
        gld16(wl + (size_t)(bcout + row0 + 64) * 4608 + kb, (short*)ab->Al + t * 8 + 2048);
    };

    auto writeB = [&](const float* xv) {    // split -> swizzled ds_write
        short8 hv, lv;
        #pragma unroll
        for (int q2 = 0; q2 < 8; ++q2) { unsigned short h, l; split2(xv[q2], h, l); hv[q2] = (short)h; lv[q2] = (short)l; }
        *(short8*)((short*)lds.s.b.Bh + swz8(row0, t & 3)) = hv;
        *(short8*)((short*)lds.s.b.Bl + swz8(row0, t & 3)) = lv;
        #pragma unroll
        for (int q2 = 0; q2 < 8; ++q2) { unsigned short h, l; split2(xv[8 + q2], h, l); hv[q2] = (short)h; lv[q2] = (short)l; }
        *(short8*)((short*)lds.s.b.Bh + swz8(row0 + 64, t & 3)) = hv;
        *(short8*)((short*)lds.s.b.Bl + swz8(row0 + 64, t & 3)) = lv;
    };

    auto compute = [&](ABuf* ab) {
        short8 ah[4], al[4];
        const int kq = lane >> 4;
        #pragma unroll
        for (int i = 0; i < 4; ++i) {
            const int r = wr * 64 + i * 16 + (lane & 15);
            ah[i] = *(const short8*)((const short*)ab->Ah + swz8(r, kq));
            al[i] = *(const short8*)((const short*)ab->Al + swz8(r, kq));
        }
        __builtin_amdgcn_s_setprio(1);
        #pragma unroll
        for (int j = 0; j < 4; ++j) {
            const int r = wc * 64 + j * 16 + (lane & 15);
            short8 bh = *(const short8*)((const short*)lds.s.b.Bh + swz8(r, kq));
            short8 bl = *(const short8*)((const short*)lds.s.b.Bl + swz8(r, kq));
            #pragma unroll
            for (int i = 0; i < 4; ++i) {
                acc[i][j] = __builtin_amdgcn_mfma_f32_16x16x32_bf16(ah[i], bh, acc[i][j], 0, 0, 0);
                acc[i][j] = __builtin_amdgcn_mfma_f32_16x16x32_bf16(ah[i], bl, acc[i][j], 0, 0, 0);
                acc[i][j] = __builtin_amdgcn_mfma_f32_16x16x32_bf16(al[i], bh, acc[i][j], 0, 0, 0);
            }
        }
        __builtin_amdgcn_s_setprio(0);
    };

    // prologue: X_0 + A_0 in flight
    loadx(0, xc);
    issueA(0, &lds.s.a[0]);

    for (int ks = 0; ks < 143; ++ks) {
        ABuf* cur = &lds.s.a[ks & 1];
        ABuf* nxt = &lds.s.a[(ks & 1) ^ 1];
        loadx(ks + 1, xn);          // 4 vmem
        issueA(ks + 1, nxt);        // 4 vmem
        writeB(xc);                 // compiler waits exactly for X_ks here
        __builtin_amdgcn_sched_barrier(0);
        asm volatile("s_waitcnt vmcnt(8) lgkmcnt(0)" ::: "memory");  // A_ks landed; B writes done
        __builtin_amdgcn_sched_barrier(0);
        __builtin_amdgcn_s_barrier();
        compute(cur);
        __builtin_amdgcn_s_barrier();
        #pragma unroll
        for (int q2 = 0; q2 < 16; ++q2) xc[q2] = xn[q2];
    }
    // tail ks = 143
    writeB(xc);
    __builtin_amdgcn_sched_barrier(0);
    asm volatile("s_waitcnt vmcnt(0) lgkmcnt(0)" ::: "memory");
    __builtin_amdgcn_sched_barrier(0);
    __builtin_amdgcn_s_barrier();
    compute(&lds.s.a[1]);

    if (MODE == 0) {
        #pragma unroll
        for (int i = 0; i < 4; ++i) {
            #pragma unroll
            for (int r = 0; r < 4; ++r) {
                const int co = bcout + wr * 64 + i * 16 + (lane >> 4) * 4 + r;
                const float sc = gamma[co] * rsqrtf(var[co] + BN_EPS);
                const float tb = (bias[co] - mean[co]) * sc + beta[co];
                const size_t rowbase = ((size_t)(b * Cc + co)) * HW;
                #pragma unroll
                for (int j = 0; j < 4; ++j) {
                    const int n = m0 + wc * 64 + j * 16 + (lane & 15);
                    const float y = fmaxf(fmaf(acc[i][j][r], sc, tb), 0.f);
                    unsigned short h, l; split2(y, h, l);
                    oh[rowbase + n] = h; ol[rowbase + n] = l;
                }
            }
        }
    } else {
        __syncthreads();   // T overlays staging planes
        #pragma unroll
        for (int i = 0; i < 4; ++i) {
            #pragma unroll
            for (int r = 0; r < 4; ++r) {
                const int cl = wr * 64 + i * 16 + (lane >> 4) * 4 + r;
                const int co = bcout + cl;
                const float sc = gamma[co] * rsqrtf(var[co] + BN_EPS);
                const float tb = (bias[co] - mean[co]) * sc + beta[co];
                #pragma unroll
                for (int j = 0; j < 4; ++j) {
                    const int nl = wc * 64 + j * 16 + (lane & 15);
                    const float y = fmaxf(fmaf(acc[i][j][r], sc, tb), 0.f);
                    lds.T[nl][cl] = (short)bf_rne(y);
                }
            }
        }
        __syncthreads();
        #pragma unroll
        for (int rep = 0; rep < 4; ++rep) {
            const int nl = (t >> 3) + rep * 32;
            const int c0l = (t & 7) * 16;
            short8 v0 = *(const short8*)&lds.T[nl][c0l];
            short8 v1 = *(const short8*)&lds.T[nl][c0l + 8];
            const size_t base = ((size_t)(b * HW + m0 + nl)) * Cc + bcout + c0l;
            *(short8*)&oh[base] = v0;
            *(short8*)&oh[base + 8] = v1;
        }
    }
    (void)ol;
}

// ---------------------------------------------------------------------------
// energy[b][c][d] = sum_n q_t[c][n] k_t[d][n], split-bf16, split-K=2.
// All-gld16 staging, double-buffered, counted vmcnt(8). grid 512 (1D swizzled).
// ---------------------------------------------------------------------------
struct EBuf { short Ah[128][32]; short Al[128][32]; short Bh[128][32]; short Bl[128][32]; }; // 32 KB

__global__ __launch_bounds__(256, 2)
void energy_k(const unsigned short* __restrict__ qh, const unsigned short* __restrict__ ql,
              const unsigned short* __restrict__ kh, const unsigned short* __restrict__ kl,
              float* __restrict__ ea, float* __restrict__ eb)
{
    __shared__ EBuf ebuf[2];   // 64 KB
    const int t = threadIdx.x;
    const int wg = (blockIdx.x & 7) * 64 + (blockIdx.x >> 3);
    const int d0 = (wg & 3) * 128;
    const int c0 = ((wg >> 2) & 3) * 128;
    const int z  = wg >> 4;
    const int b  = z >> 1;
    const int nb0 = (z & 1) * 2048;
    float* __restrict__ eo = (z & 1) ? eb : ea;
    const int lane = t & 63, wave = t >> 6, wr = wave >> 1, wc = wave & 1;
    const int row0 = t >> 2;
    const int qlog = (t & 3) ^ ((t >> 3) & 3);

    const size_t qb = (size_t)b * Cc * HW;
    f32x4 acc[4][4] = {};

    auto issue = [&](int ks, EBuf* e8) {   // 8 gld16
        const size_t nb = nb0 + ks * 32 + qlog * 8;
        gld16(qh + qb + (size_t)(c0 + row0)      * HW + nb, (short*)e8->Ah + t * 8);
        gld16(qh + qb + (size_t)(c0 + row0 + 64) * HW + nb, (short*)e8->Ah + t * 8 + 2048);
        gld16(ql + qb + (size_t)(c0 + row0)      * HW + nb, (short*)e8->Al + t * 8);
        gld16(ql + qb + (size_t)(c0 + row0 + 64) * HW + nb, (short*)e8->Al + t * 8 + 2048);
        gld16(kh + qb + (size_t)(d0 + row0)      * HW + nb, (short*)e8->Bh + t * 8);
        gld16(kh + qb + (size_t)(d0 + row0 + 64) * HW + nb, (short*)e8->Bh + t * 8 + 2048);
        gld16(kl + qb + (size_t)(d0 + row0)      * HW + nb, (short*)e8->Bl + t * 8);
        gld16(kl + qb + (size_t)(d0 + row0 + 64) * HW + nb, (short*)e8->Bl + t * 8 + 2048);
    };
    auto compute = [&](EBuf* e8) {
        short8 ah[4], al[4];
        const int kq = lane >> 4;
        #pragma unroll
        for (int i = 0; i < 4; ++i) {
            const int r = wr * 64 + i * 16 + (lane & 15);
            ah[i] = *(const short8*)((const short*)e8->Ah + swz8(r, kq));
            al[i] = *(const short8*)((const short*)e8->Al + swz8(r, kq));
        }
        __builtin_amdgcn_s_setprio(1);
        #pragma unroll
        for (int j = 0; j < 4; ++j) {
            const int r = wc * 64 + j * 16 + (lane & 15);
            short8 bh = *(const short8*)((const short*)e8->Bh + swz8(r, kq));
            short8 bl = *(const short8*)((const short*)e8->Bl + swz8(r, kq));
            #pragma unroll
            for (int i = 0; i < 4; ++i) {
                acc[i][j] = __builtin_amdgcn_mfma_f32_16x16x32_bf16(ah[i], bh, acc[i][j], 0, 0, 0);
                acc[i][j] = __builtin_amdgcn_mfma_f32_16x16x32_bf16(ah[i], bl, acc[i][j], 0, 0, 0);
                acc[i][j] = __builtin_amdgcn_mfma_f32_16x16x32_bf16(al[i], bh, acc[i][j], 0, 0, 0);
            }
        }
        __builtin_amdgcn_s_setprio(0);
    };

    issue(0, &ebuf[0]);
    for (int ks = 0; ks < 63; ++ks) {
        issue(ks + 1, &ebuf[(ks & 1) ^ 1]);
        __builtin_amdgcn_sched_barrier(0);
        asm volatile("s_waitcnt vmcnt(8)" ::: "memory");
        __builtin_amdgcn_sched_barrier(0);
        __builtin_amdgcn_s_barrier();
        compute(&ebuf[ks & 1]);
        __builtin_amdgcn_s_barrier();
    }
    __builtin_amdgcn_sched_barrier(0);
    asm volatile("s_waitcnt vmcnt(0)" ::: "memory");
    __builtin_amdgcn_sched_barrier(0);
    __builtin_amdgcn_s_barrier();
    compute(&ebuf[1]);

    #pragma unroll
    for (int i = 0; i < 4; ++i)
        #pragma unroll
        for (int r = 0; r < 4; ++r) {
            const int c = c0 + wr * 64 + i * 16 + (lane >> 4) * 4 + r;
            #pragma unroll
            for (int j = 0; j < 4; ++j) {
                const int d = d0 + wc * 64 + j * 16 + (lane & 15);
                eo[((size_t)(b * Cc) + c) * Cc + d] = acc[i][j][r];
            }
        }
}

// ---------------------------------------------------------------------------
// softmax rows (B*C = 8192), adds split-K partials, writes bf16 attn
// ---------------------------------------------------------------------------
__global__ __launch_bounds__(256)
void softmax_k(const float* __restrict__ ea, const float* __restrict__ eb,
               unsigned short* __restrict__ attn)
{
    __shared__ float red[256];
    const int r = blockIdx.x, t = threadIdx.x;
    const size_t base = (size_t)r * Cc;
    const float v0 = ea[base + t] + eb[base + t];
    const float v1 = ea[base + t + 256] + eb[base + t + 256];

    red[t] = fmaxf(v0, v1);
    __syncthreads();
    for (int s = 128; s > 0; s >>= 1) {
        if (t < s) red[t] = fmaxf(red[t], red[t + s]);
        __syncthreads();
    }
    const float mx = red[0];
    __syncthreads();
    const float e0 = expf(v0 - mx);
    const float e1 = expf(v1 - mx);
    red[t] = e0 + e1;
    __syncthreads();
    for (int s = 128; s > 0; s >>= 1) {
        if (t < s) red[t] += red[t + s];
        __syncthreads();
    }
    const float inv = 1.0f / red[0];
    attn[base + t]       = bf_rne(e0 * inv);
    attn[base + t + 256] = bf_rne(e1 * inv);
}

// ---------------------------------------------------------------------------
// pv: out[b][c*HW+n] = aw * sum_d attn[c][d] v[n][d] + x[same flat].
// grid 2048 (1D swizzled); double-buffered gld16, vmcnt(4).
// ---------------------------------------------------------------------------
struct PvBuf { short Ah[128][32]; short Bh[128][32]; };  // 16 KB

__global__ __launch_bounds__(256, 4)
void pv_k(const unsigned short* __restrict__ attn, const unsigned short* __restrict__ v,
          const float* __restrict__ x, const float* __restrict__ aw,
          float* __restrict__ out)
{
    __shared__ PvBuf pbuf[2];   // 32 KB
    const int t = threadIdx.x;
    const int wg = (blockIdx.x & 7) * 256 + (blockIdx.x >> 3);
    const int m0 = (wg & 31) * 128;
    const int c0 = ((wg >> 5) & 3) * 128;
    const int b  = wg >> 7;
    const int lane = t & 63, wave = t >> 6, wr = wave >> 1, wc = wave & 1;
    const int row0 = t >> 2;
    const int qlog = (t & 3) ^ ((t >> 3) & 3);

    f32x4 acc[4][4] = {};
    const size_t ab = (size_t)b * Cc * Cc;
    const size_t vb = (size_t)b * HW * Cc;

    auto issue = [&](int ks, PvBuf* pb) {   // 4 gld16
        const size_t db = ks * 32 + qlog * 8;
        gld16(attn + ab + (size_t)(c0 + row0)      * Cc + db, (short*)pb->Ah + t * 8);
        gld16(attn + ab + (size_t)(c0 + row0 + 64) * Cc + db, (short*)pb->Ah + t * 8 + 2048);
        gld16(v + vb + (size_t)(m0 + row0)      * Cc + db, (short*)pb->Bh + t * 8);
        gld16(v + vb + (size_t)(m0 + row0 + 64) * Cc + db, (short*)pb->Bh + t * 8 + 2048);
    };
    auto compute = [&](PvBuf* pb) {
        short8 ah[4];
        const int kq = lane >> 4;
        #pragma unroll
        for (int i = 0; i < 4; ++i)
            ah[i] = *(const short8*)((const short*)pb->Ah + swz8(wr * 64 + i * 16 + (lane & 15), kq));
        __builtin_amdgcn_s_setprio(1);
        #pragma unroll
        for (int j = 0; j < 4; ++j) {
            short8 bh = *(const short8*)((const short*)pb->Bh + swz8(wc * 64 + j * 16 + (lane & 15), kq));
            #pragma unroll
            for (int i = 0; i < 4; ++i)
                acc[i][j] = __builtin_amdgcn_mfma_f32_16x16x32_bf16(ah[i], bh, acc[i][j], 0, 0, 0);
        }
        __builtin_amdgcn_s_setprio(0);
    };

    issue(0, &pbuf[0]);
    for (int ks = 0; ks < 15; ++ks) {
        issue(ks + 1, &pbuf[(ks & 1) ^ 1]);
        __builtin_amdgcn_sched_barrier(0);
        asm volatile("s_waitcnt vmcnt(4)" ::: "memory");
        __builtin_amdgcn_sched_barrier(0);
        __builtin_amdgcn_s_barrier();
        compute(&pbuf[ks & 1]);
        __builtin_amdgcn_s_barrier();
    }
    __builtin_amdgcn_sched_barrier(0);
    asm volatile("s_waitcnt vmcnt(0)" ::: "memory");
    __builtin_amdgcn_sched_barrier(0);
    __builtin_amdgcn_s_barrier();
    compute(&pbuf[1]);

    const float a_w = aw[0];
    #pragma unroll
    for (int i = 0; i < 4; ++i)
        #pragma unroll
        for (int r = 0; r < 4; ++r) {
            const int c = c0 + wr * 64 + i * 16 + (lane >> 4) * 4 + r;
            #pragma unroll
            for (int j = 0; j < 4; ++j) {
                const int n = m0 + wc * 64 + j * 16 + (lane & 15);
                const size_t idx = (size_t)b * ((size_t)Cc * HW) + (size_t)c * HW + n;
                out[idx] = fmaf(a_w, acc[i][j][r], x[idx]);
            }
        }
}

// ---------------------------------------------------------------------------
extern "C" void kernel_launch(void* const* d_in, const int* in_sizes, int n_in,
                              void* d_out, int out_size, void* d_ws, size_t ws_size,
                              hipStream_t stream)
{
    (void)in_sizes; (void)n_in; (void)out_size; (void)ws_size;
    const float* x   = (const float*)d_in[0];
    const float* Wq  = (const float*)d_in[1];
    const float* bq  = (const float*)d_in[2];
    const float* Wk  = (const float*)d_in[3];
    const float* bk  = (const float*)d_in[4];
    const float* Wv  = (const float*)d_in[5];
    const float* bvv = (const float*)d_in[6];
    const float* qg  = (const float*)d_in[7];
    const float* qbt = (const float*)d_in[8];
    const float* qm  = (const float*)d_in[9];
    const float* qv  = (const float*)d_in[10];
    const float* kg  = (const float*)d_in[11];
    const float* kbt = (const float*)d_in[12];
    const float* km  = (const float*)d_in[13];
    const float* kv  = (const float*)d_in[14];
    const float* vg  = (const float*)d_in[15];
    const float* vbt = (const float*)d_in[16];
    const float* vm  = (const float*)d_in[17];
    const float* vvr = (const float*)d_in[18];
    const float* aw  = (const float*)d_in[19];
    float* out = (float*)d_out;

    char* w = (char*)d_ws;
    unsigned short* wt_h = (unsigned short*)(w);
    unsigned short* wt_l = (unsigned short*)(w + 4718592);
    unsigned short* q_h  = (unsigned short*)(w + 9437184);
    unsigned short* q_l  = (unsigned short*)(w + 76546048);
    unsigned short* k_h  = (unsigned short*)(w + 143654912);
    unsigned short* k_l  = (unsigned short*)(w + 210763776);
    unsigned short* v_b  = (unsigned short*)(w + 277872640);
    float*          e_a  = (float*)(w + 344981504);
    float*          e_b  = (float*)(w + 361758720);
    unsigned short* attn = (unsigned short*)(w + 378535936);
    // total = 386,924,544 bytes (< round-1-proven 419,430,400)

    const dim3 blk(256);
    const dim3 wgrid(16, 16, 9);

    wsplit_k<<<wgrid, blk, 0, stream>>>(Wq, wt_h, wt_l);
    conv_k<0><<<dim3(2048), blk, 0, stream>>>(x, wt_h, wt_l, bq, qg, qbt, qm, qv, q_h, q_l);
    wsplit_k<<<wgrid, blk, 0, stream>>>(Wk, wt_h, wt_l);
    conv_k<0><<<dim3(2048), blk, 0, stream>>>(x, wt_h, wt_l, bk, kg, kbt, km, kv, k_h, k_l);
    wsplit_k<<<wgrid, blk, 0, stream>>>(Wv, wt_h, wt_l);
    conv_k<1><<<dim3(2048), blk, 0, stream>>>(x, wt_h, wt_l, bvv, vg, vbt, vm, vvr, v_b, nullptr);

    energy_k<<<dim3(512), blk, 0, stream>>>(q_h, q_l, k_h, k_l, e_a, e_b);
    softmax_k<<<dim3(8192), blk, 0, stream>>>(e_a, e_b, attn);
    pv_k<<<dim3(2048), blk, 0, stream>>>(attn, v_b, x, aw, out);
}